// Round 2
// baseline (773.406 us; speedup 1.0000x reference)
//
#include <hip/hip_runtime.h>
#include <cstdint>
#include <cstddef>

#define IN_F   512
#define OUT_F  100000
#define BATCH_N 1024
#define BM 128
#define BN 128
#define BK 32

#define SCALE_F 20.0f
#define COS_M 0.8775825618903728f   // cos(0.5)
#define SIN_M 0.4794255386042030f   // sin(0.5)

typedef short s16x8 __attribute__((ext_vector_type(8)));
typedef float f32x4 __attribute__((ext_vector_type(4)));
typedef unsigned int u32x4 __attribute__((ext_vector_type(4)));

__device__ __forceinline__ unsigned int f2bf_bits(float x) {
  union { float f; unsigned int u; } v; v.f = x;
  return (v.u + 0x7fffu + ((v.u >> 16) & 1u)) >> 16;  // RNE f32->bf16
}

// RNE f32 pair -> packed bf16x2 (hardware cvt, 1 inst)
__device__ __forceinline__ unsigned int cvt_pk_bf16(float lo, float hi) {
  unsigned int r;
  asm("v_cvt_pk_bf16_f32 %0, %1, %2" : "=v"(r) : "v"(lo), "v"(hi));
  return r;
}

// One wave per row: L2-normalize a 512-float row, emit bf16.
// Only used for the 1024 feature rows now (weights are fused into the GEMM).
__global__ __launch_bounds__(256) void normalize_rows_bf16(
    const float* __restrict__ in, unsigned short* __restrict__ out, int rows) {
  const int gw   = (int)((blockIdx.x * 256u + threadIdx.x) >> 6);
  const int lane = threadIdx.x & 63;
  if (gw >= rows) return;
  const f32x4* rp = (const f32x4*)(in + (size_t)gw * IN_F);
  f32x4 a = rp[lane];
  f32x4 b = rp[lane + 64];
  float s = a.x*a.x + a.y*a.y + a.z*a.z + a.w*a.w
          + b.x*b.x + b.y*b.y + b.z*b.z + b.w*b.w;
  #pragma unroll
  for (int off = 32; off > 0; off >>= 1) s += __shfl_xor(s, off, 64);
  const float sc = 1.0f / fmaxf(sqrtf(s), 1e-12f);
  uint2 q0, q1;
  q0.x = f2bf_bits(a.x * sc) | (f2bf_bits(a.y * sc) << 16);
  q0.y = f2bf_bits(a.z * sc) | (f2bf_bits(a.w * sc) << 16);
  q1.x = f2bf_bits(b.x * sc) | (f2bf_bits(b.y * sc) << 16);
  q1.y = f2bf_bits(b.z * sc) | (f2bf_bits(b.w * sc) << 16);
  uint2* op = (uint2*)(out + (size_t)gw * IN_F);
  op[lane]      = q0;
  op[lane + 64] = q1;
}

// 128x128 tile bf16 MFMA GEMM with FUSED weight normalization.
// A: [1024,512] bf16 (pre-normalized features).
// W: [100000,512] f32 RAW weights -- converted to bf16 in-register during
//    staging; per-row sum-of-squares accumulated alongside; the row norm is
//    applied to the dot product in the epilogue (cos = (f.w)/||w||).
// This deletes the separate 100k-row normalize pass (~205MB read + 102MB
// write + 102MB re-read) in exchange for reading W as f32 here (205MB,
// panel re-reads L2-amortized by the XCD swizzle).
__global__ __launch_bounds__(256) void arcface_gemm(
    const unsigned short* __restrict__ A,
    const float* __restrict__ W,
    const int* __restrict__ targets,
    float* __restrict__ out) {
  __shared__ unsigned short As[BM * BK];
  __shared__ unsigned short Bs[BN * BK];
  __shared__ int   s_tgt[BM];
  __shared__ float s_inv[BN];

  const int tid  = threadIdx.x;
  const int lane = tid & 63;
  const int wid  = tid >> 6;          // 4 waves
  const int wm   = wid >> 1;          // 2x2 wave grid over 128x128
  const int wn   = wid & 1;

  // --- XCD-aware bijective swizzle (T1): each XCD owns contiguous N-panels
  // with all 8 of their M-blocks -> B panel fetched from HBM once per XCD.
  const int L    = (int)(blockIdx.x + gridDim.x * blockIdx.y);
  const int cpx  = (int)(gridDim.x * gridDim.y) >> 3;   // 782
  const int newL = (L & 7) * cpx + (L >> 3);
  const int m0   = (newL & 7) * BM;
  const int n0   = (newL >> 3) * BN;

  if (tid < BM) s_tgt[tid] = targets[m0 + tid];

  f32x4 acc[4][4];
  const f32x4 zero = {0.f, 0.f, 0.f, 0.f};
  #pragma unroll
  for (int i = 0; i < 4; ++i)
    #pragma unroll
    for (int j = 0; j < 4; ++j) acc[i][j] = zero;

  const int lrow = lane >> 2;          // 0..15 : row within a 16-row staging chunk
  const int lcol = (lane & 3) * 8;     // 0,8,16,24 : element col offset
  const int ra0  = wid * 16;           // this wave's first chunk

  const int lc = lane & 15;            // MFMA fragment col / row-in-16
  const int lq = lane >> 4;            // quad
  const int kq = lq * 8;               // k offset within BK for A/B fragments

  // Fixed B row pointers (clamp for the 100000 % 128 tail tile).
  int nr0 = n0 + ra0 + lrow;       if (nr0 >= OUT_F) nr0 = OUT_F - 1;
  int nr1 = n0 + ra0 + 64 + lrow;  if (nr1 >= OUT_F) nr1 = OUT_F - 1;
  const float* wp0 = W + (size_t)nr0 * IN_F + lcol;
  const float* wp1 = W + (size_t)nr1 * IN_F + lcol;

  float ss0 = 0.0f, ss1 = 0.0f;       // per-(lane,row-chunk) partial sum(w^2)

  for (int kt = 0; kt < IN_F / BK; ++kt) {
    const int k0 = kt * BK;

    // ---- B: global f32 -> regs. Issued BEFORE the barrier (touches no LDS)
    // so HBM latency hides under other waves' barrier drain (T14).
    f32x4 u0 = *(const f32x4*)(wp0 + k0);
    f32x4 u1 = *(const f32x4*)(wp0 + k0 + 4);
    f32x4 v0 = *(const f32x4*)(wp1 + k0);
    f32x4 v1 = *(const f32x4*)(wp1 + k0 + 4);

    if (kt) __syncthreads();   // prev iteration's ds_reads done before overwrite

    // ---- A: direct global->LDS 16B (two 16-row chunks per wave) ----
    {
      const unsigned short* g0 = A + (size_t)(m0 + ra0 + lrow) * IN_F + k0 + lcol;
      __builtin_amdgcn_global_load_lds(
          (const __attribute__((address_space(1))) void*)g0,
          (__attribute__((address_space(3))) void*)&As[ra0 * BK], 16, 0, 0);
      const unsigned short* g1 = A + (size_t)(m0 + ra0 + 64 + lrow) * IN_F + k0 + lcol;
      __builtin_amdgcn_global_load_lds(
          (const __attribute__((address_space(1))) void*)g1,
          (__attribute__((address_space(3))) void*)&As[(ra0 + 64) * BK], 16, 0, 0);
    }

    // ---- B: sumsq + convert + LDS write ----
    ss0 += u0.x*u0.x + u0.y*u0.y + u0.z*u0.z + u0.w*u0.w
         + u1.x*u1.x + u1.y*u1.y + u1.z*u1.z + u1.w*u1.w;
    ss1 += v0.x*v0.x + v0.y*v0.y + v0.z*v0.z + v0.w*v0.w
         + v1.x*v1.x + v1.y*v1.y + v1.z*v1.z + v1.w*v1.w;
    u32x4 pb0 = { cvt_pk_bf16(u0.x, u0.y), cvt_pk_bf16(u0.z, u0.w),
                  cvt_pk_bf16(u1.x, u1.y), cvt_pk_bf16(u1.z, u1.w) };
    *(u32x4*)&Bs[(ra0 + lrow) * BK + lcol] = pb0;
    u32x4 pb1 = { cvt_pk_bf16(v0.x, v0.y), cvt_pk_bf16(v0.z, v0.w),
                  cvt_pk_bf16(v1.x, v1.y), cvt_pk_bf16(v1.z, v1.w) };
    *(u32x4*)&Bs[(ra0 + 64 + lrow) * BK + lcol] = pb1;

    __syncthreads();   // drains vmcnt (gload_lds) + lgkm (ds_write) per HIP semantics

    // ---- fragments + 16 MFMA ----
    s16x8 afr[4], bfr[4];
    #pragma unroll
    for (int i = 0; i < 4; ++i)
      afr[i] = *(const s16x8*)&As[(wm * 64 + i * 16 + lc) * BK + kq];
    #pragma unroll
    for (int j = 0; j < 4; ++j)
      bfr[j] = *(const s16x8*)&Bs[(wn * 64 + j * 16 + lc) * BK + kq];
    #pragma unroll
    for (int i = 0; i < 4; ++i)
      #pragma unroll
      for (int j = 0; j < 4; ++j)
        acc[i][j] = __builtin_amdgcn_mfma_f32_16x16x32_bf16(afr[i], bfr[j], acc[i][j], 0, 0, 0);
  }

  // ---- per-B-row inverse norm: reduce the 4 lanes sharing a row ----
  ss0 += __shfl_xor(ss0, 1, 64);  ss0 += __shfl_xor(ss0, 2, 64);
  ss1 += __shfl_xor(ss1, 1, 64);  ss1 += __shfl_xor(ss1, 2, 64);
  if ((lane & 3) == 0) {
    s_inv[ra0 + lrow]      = 1.0f / fmaxf(sqrtf(ss0), 1e-12f);
    s_inv[ra0 + 64 + lrow] = 1.0f / fmaxf(sqrtf(ss1), 1e-12f);
  }
  __syncthreads();

  // ---- epilogue: normalize, clamp, margin at target col, scale, store ----
  // Row-contiguous order + nontemporal (write-once stream, keep LLC for W).
  const int cbase = n0 + wn * 64;
  float winv[4];
  #pragma unroll
  for (int j = 0; j < 4; ++j) winv[j] = s_inv[wn * 64 + j * 16 + lc];
  #pragma unroll
  for (int i = 0; i < 4; ++i) {
    #pragma unroll
    for (int r = 0; r < 4; ++r) {
      const int lrw = wm * 64 + i * 16 + lq * 4 + r;  // local row 0..127
      const int tgt = s_tgt[lrw];
      float* orow = out + (size_t)(m0 + lrw) * OUT_F;
      #pragma unroll
      for (int j = 0; j < 4; ++j) {
        const int col = cbase + j * 16 + lc;
        if (col >= OUT_F) continue;
        float x = acc[i][j][r] * winv[j];
        x = fminf(1.0f, fmaxf(-1.0f, x));
        float y = (col == tgt)
                    ? (x * COS_M - sqrtf(fmaxf(1.0f - x * x, 0.0f)) * SIN_M)
                    : x;
        __builtin_nontemporal_store(SCALE_F * y, &orow[col]);
      }
    }
  }
}

extern "C" void kernel_launch(void* const* d_in, const int* in_sizes, int n_in,
                              void* d_out, int out_size, void* d_ws, size_t ws_size,
                              hipStream_t stream) {
  const float* features = (const float*)d_in[0];
  const int*   targets  = (const int*)d_in[1];
  const float* weights  = (const float*)d_in[2];
  float* out = (float*)d_out;

  unsigned short* fbf = (unsigned short*)d_ws;   // 1024*512 bf16

  // normalize features: 1024 rows -> 1024 waves -> 256 blocks
  normalize_rows_bf16<<<(BATCH_N * 64 + 255) / 256, 256, 0, stream>>>(features, fbf, BATCH_N);

  dim3 grid(BATCH_N / BM, (OUT_F + BN - 1) / BN);
  arcface_gemm<<<grid, 256, 0, stream>>>(fbf, weights, targets, out);
}